// Round 9
// baseline (270.053 us; speedup 1.0000x reference)
//
#include <hip/hip_runtime.h>
#include <math.h>

#define N_NODES 16384
#define IN_DIM  512
#define HID_DIM 256
#define OUT_DIM 128
#define MAXDEG  128

typedef float f4v __attribute__((ext_vector_type(4)));
typedef float f32x4 __attribute__((ext_vector_type(4)));
typedef short bf16x8 __attribute__((ext_vector_type(8)));

__device__ __forceinline__ float bf2f(unsigned short u) {
    return __uint_as_float(((unsigned int)u) << 16);
}
__device__ __forceinline__ unsigned short f2bf(float f) {
    unsigned int u = __float_as_uint(f);
    return (unsigned short)((u + 0x7FFFu + ((u >> 16) & 1u)) >> 16);
}

// ---------------------------------------------------------------------------
// W1 [512][256] f32  ->  W1T [256][512] bf16 (LDS tile transpose, 32 blocks).
// ---------------------------------------------------------------------------
__global__ __launch_bounds__(256) void w1t_kernel(
    const float* __restrict__ W1, unsigned short* __restrict__ W1T) {
    __shared__ float tile[64][65];
    const int kb = blockIdx.x * 64, cb = blockIdx.y * 64;
    for (int i = threadIdx.x; i < 64 * 64; i += 256) {
        const int r = i >> 6, c = i & 63;          // read coalesced over c
        tile[r][c] = W1[(size_t)(kb + r) * HID_DIM + cb + c];
    }
    __syncthreads();
    for (int i = threadIdx.x; i < 64 * 64; i += 256) {
        const int c = i >> 6, k = i & 63;          // write coalesced over k
        W1T[(size_t)(cb + c) * IN_DIM + kb + k] = f2bf(tile[k][c]);
    }
}

// ---------------------------------------------------------------------------
// gemm1 via MFMA: h1 = bf16(x @ W1). 256 blocks (1/CU) x 256 thr (4 waves).
// Block tile 64x256 (full N), K-chunk 64, double-buffered LDS (92 KB).
// Wave w: rows m0+16w..+15, 16 col-tiles. Frag layout (round-8 proven):
// A row=l&15, k=(l>>4)*8+j; B col=l&15, same k; C/D col=l&15, row=(l>>4)*4+r.
// LDS row stride 72 bf16 = 144 B (9x16B: b128-aligned, 2-way bank = free).
// ---------------------------------------------------------------------------
__global__ __launch_bounds__(256) void gemm1_mfma_kernel(
    const float* __restrict__ X, const unsigned short* __restrict__ W1T,
    unsigned short* __restrict__ H1) {
    __shared__ unsigned short xs[2][64][72];     // 18 KB
    __shared__ unsigned short ws[2][256][72];    // 72 KB
    const int tid = threadIdx.x;
    const int m0  = blockIdx.x * 64;

    auto stage = [&](int buf, int kc) {
        const int k0 = kc * 64;
        #pragma unroll
        for (int idx = tid, j = 0; j < 4; ++j, idx += 256) {   // xs: 64x64 f32->bf16
            const int r = idx >> 4, kk = (idx & 15) * 4;
            const float4 v = *(const float4*)(X + (size_t)(m0 + r) * IN_DIM + k0 + kk);
            ushort4 o;
            o.x = f2bf(v.x); o.y = f2bf(v.y); o.z = f2bf(v.z); o.w = f2bf(v.w);
            *(ushort4*)&xs[buf][r][kk] = o;
        }
        #pragma unroll
        for (int idx = tid, j = 0; j < 8; ++j, idx += 256) {   // ws: 256x64 bf16 copy
            const int r = idx >> 3, g = (idx & 7) * 8;
            *(uint4*)&ws[buf][r][g] =
                *(const uint4*)(W1T + (size_t)r * IN_DIM + k0 + g);
        }
    };

    stage(0, 0);
    __syncthreads();
    const int wave = tid >> 6, lane = tid & 63;
    const int rloc = wave * 16 + (lane & 15);
    const int koff = (lane >> 4) * 8;
    f32x4 acc[16];
    #pragma unroll
    for (int i = 0; i < 16; ++i) acc[i] = {0.f, 0.f, 0.f, 0.f};
    for (int kc = 0; kc < 8; ++kc) {
        const int buf = kc & 1;
        if (kc < 7) stage(buf ^ 1, kc + 1);      // prefetch next chunk
        #pragma unroll
        for (int ks = 0; ks < 2; ++ks) {
            const bf16x8 af = *(const bf16x8*)&xs[buf][rloc][ks * 32 + koff];
            #pragma unroll
            for (int nt = 0; nt < 16; ++nt) {
                const bf16x8 bfr =
                    *(const bf16x8*)&ws[buf][nt * 16 + (lane & 15)][ks * 32 + koff];
                acc[nt] = __builtin_amdgcn_mfma_f32_16x16x32_bf16(af, bfr, acc[nt],
                                                                  0, 0, 0);
            }
        }
        __syncthreads();
    }
    const int orow = m0 + wave * 16 + (lane >> 4) * 4;
    #pragma unroll
    for (int nt = 0; nt < 16; ++nt)
        #pragma unroll
        for (int r = 0; r < 4; ++r)
            H1[(size_t)(orow + r) * HID_DIM + nt * 16 + (lane & 15)] =
                f2bf(acc[nt][r]);
}

// ---------------------------------------------------------------------------
// Pure scan: 4096 blocks, 4 rows/block (wave/row), nontemporal loads,
// 2-chunk unroll. Builds adj lists + deg^-1/2. Full occupancy, no GEMM
// interference.
// ---------------------------------------------------------------------------
__global__ __launch_bounds__(256) void scan_kernel(
    const float* __restrict__ A,
    int* __restrict__ adj, int* __restrict__ cnt, float* __restrict__ din) {
    const int lane = threadIdx.x & 63;
    const int row  = blockIdx.x * 4 + (threadIdx.x >> 6);
    const f4v* arow = (const f4v*)(A + (size_t)row * N_NODES);
    const unsigned long long lt = (1ull << lane) - 1ull;
    int base = 0;
    for (int chunk = 0; chunk < N_NODES / 256; chunk += 2) {
        const f4v v0 = __builtin_nontemporal_load(&arow[chunk * 64 + lane]);
        const f4v v1 = __builtin_nontemporal_load(&arow[chunk * 64 + 64 + lane]);
        const float vv[8] = {v0.x, v0.y, v0.z, v0.w, v1.x, v1.y, v1.z, v1.w};
        #pragma unroll
        for (int h = 0; h < 2; ++h) {
            const int c0 = (chunk + h) * 256 + lane * 4;
            #pragma unroll
            for (int i = 0; i < 4; ++i) {
                const bool nz = vv[h * 4 + i] != 0.f;
                const unsigned long long m = __ballot(nz);
                if (nz) {
                    const int p = base + __popcll(m & lt);
                    if (p < MAXDEG) adj[row * MAXDEG + p] = c0 + i;
                }
                base += __popcll(m);
            }
        }
    }
    if (lane == 0) {
        cnt[row] = base < MAXDEG ? base : MAXDEG;
        din[row] = base > 0 ? 1.0f / sqrtf((float)base) : 0.0f;
    }
}

// ---------------------------------------------------------------------------
// agg1: 4 nodes/block (wave per node), bf16 gathers of h1, f32 accumulate,
// ELU + row L2-norm. Writes z1 f32 (output) AND z1b bf16 (layer-2 input).
// ---------------------------------------------------------------------------
__global__ __launch_bounds__(256) void agg1_kernel(
    const unsigned short* __restrict__ h1, const int* __restrict__ adj,
    const int* __restrict__ cnt, const float* __restrict__ din,
    const float* __restrict__ b1, float* __restrict__ z1,
    unsigned short* __restrict__ z1b) {
    __shared__ int   s_adj[4][MAXDEG];
    __shared__ float s_dsc[4][MAXDEG];
    const int wid  = threadIdx.x >> 6;
    const int lane = threadIdx.x & 63;
    const int node = blockIdx.x * 4 + wid;
    const int n    = cnt[node];
    for (int e = lane; e < n; e += 64) {
        const int src = adj[node * MAXDEG + e];
        s_adj[wid][e] = src;
        s_dsc[wid][e] = din[src];
    }
    __syncthreads();
    const int c0 = lane * 4;
    float acc[4] = {};
    #define GATHER(idx_)                                                       \
        do {                                                                   \
            const int ei_ = (idx_);                                            \
            const ushort4 hv_ = *(const ushort4*)(                             \
                h1 + (size_t)s_adj[wid][ei_] * HID_DIM + c0);                  \
            const float w_ = s_dsc[wid][ei_];                                  \
            acc[0] += bf2f(hv_.x) * w_; acc[1] += bf2f(hv_.y) * w_;            \
            acc[2] += bf2f(hv_.z) * w_; acc[3] += bf2f(hv_.w) * w_;            \
        } while (0)
    int e = 0;
    for (; e + 8 <= n; e += 8) {
        #pragma unroll
        for (int uu = 0; uu < 8; ++uu) GATHER(e + uu);
    }
    for (; e < n; ++e) GATHER(e);
    #undef GATHER
    const float dn = din[node];
    float val[4];
    float ss = 0.f;
    #pragma unroll
    for (int u = 0; u < 4; ++u) {
        float v = acc[u] * dn + b1[c0 + u];
        v = v > 0.f ? v : expm1f(v);
        val[u] = v;
        ss += v * v;
    }
    #pragma unroll
    for (int off = 32; off > 0; off >>= 1) ss += __shfl_xor(ss, off, 64);
    const float inv = 1.0f / fmaxf(sqrtf(ss), 1e-12f);
    #pragma unroll
    for (int u = 0; u < 4; ++u) val[u] *= inv;
    *(float4*)(z1 + (size_t)node * HID_DIM + c0) =
        make_float4(val[0], val[1], val[2], val[3]);
    ushort4 ob;
    ob.x = f2bf(val[0]); ob.y = f2bf(val[1]);
    ob.z = f2bf(val[2]); ob.w = f2bf(val[3]);
    *(ushort4*)(z1b + (size_t)node * HID_DIM + c0) = ob;
}

// ---------------------------------------------------------------------------
// gemm2 via MFMA: h2 = bf16(z1b @ W2). Proven in round 8.
// ---------------------------------------------------------------------------
__global__ __launch_bounds__(256) void gemm2_mfma_kernel(
    const unsigned short* __restrict__ Z, const float* __restrict__ W2,
    unsigned short* __restrict__ H2) {
    __shared__ unsigned short W2t[OUT_DIM][HID_DIM + 8];   // 66 KB
    const int tid = threadIdx.x;
    for (int idx = tid; idx < OUT_DIM * HID_DIM / 2; idx += 256) {
        const int n = idx >> 7, kk = (idx & 127) * 2;
        W2t[n][kk]     = f2bf(W2[(size_t)kk * OUT_DIM + n]);
        W2t[n][kk + 1] = f2bf(W2[(size_t)(kk + 1) * OUT_DIM + n]);
    }
    __syncthreads();
    const int wave = tid >> 6, lane = tid & 63;
    const int m0   = blockIdx.x * 64 + wave * 16;
    const int arow = m0 + (lane & 15);
    const int koff = (lane >> 4) * 8;
    bf16x8 afrag[8];
    #pragma unroll
    for (int ks = 0; ks < 8; ++ks)
        afrag[ks] = *(const bf16x8*)(Z + (size_t)arow * HID_DIM + ks * 32 + koff);
    const int orow = m0 + (lane >> 4) * 4;
    #pragma unroll
    for (int nt = 0; nt < 8; ++nt) {
        f32x4 acc = {0.f, 0.f, 0.f, 0.f};
        const unsigned short* wcol = &W2t[nt * 16 + (lane & 15)][koff];
        #pragma unroll
        for (int ks = 0; ks < 8; ++ks) {
            const bf16x8 bfrag = *(const bf16x8*)(wcol + ks * 32);
            acc = __builtin_amdgcn_mfma_f32_16x16x32_bf16(afrag[ks], bfrag, acc,
                                                          0, 0, 0);
        }
        #pragma unroll
        for (int r = 0; r < 4; ++r)
            H2[(size_t)(orow + r) * OUT_DIM + nt * 16 + (lane & 15)] =
                f2bf(acc[r]);
    }
}

// ---------------------------------------------------------------------------
// agg2: 4 nodes/block (wave per node), bf16 gathers of h2, bias + L2-norm.
// ---------------------------------------------------------------------------
__global__ __launch_bounds__(256) void agg2_kernel(
    const unsigned short* __restrict__ h, const int* __restrict__ adj,
    const int* __restrict__ cnt, const float* __restrict__ din,
    const float* __restrict__ bias, float* __restrict__ out) {
    __shared__ int   s_adj[4][MAXDEG];
    __shared__ float s_dsc[4][MAXDEG];
    const int wid  = threadIdx.x >> 6;
    const int lane = threadIdx.x & 63;
    const int node = blockIdx.x * 4 + wid;
    const int n    = cnt[node];
    for (int e = lane; e < n; e += 64) {
        const int src = adj[node * MAXDEG + e];
        s_adj[wid][e] = src;
        s_dsc[wid][e] = din[src];
    }
    __syncthreads();
    const int c0 = lane * 2;
    float acc[2] = {};
    #define GATHER(idx_)                                                       \
        do {                                                                   \
            const int ei_ = (idx_);                                            \
            const ushort2 hv_ = *(const ushort2*)(                             \
                h + (size_t)s_adj[wid][ei_] * OUT_DIM + c0);                   \
            const float w_ = s_dsc[wid][ei_];                                  \
            acc[0] += bf2f(hv_.x) * w_; acc[1] += bf2f(hv_.y) * w_;            \
        } while (0)
    int e = 0;
    for (; e + 8 <= n; e += 8) {
        #pragma unroll
        for (int uu = 0; uu < 8; ++uu) GATHER(e + uu);
    }
    for (; e < n; ++e) GATHER(e);
    #undef GATHER
    const float dn = din[node];
    const float v0 = acc[0] * dn + bias[c0];
    const float v1 = acc[1] * dn + bias[c0 + 1];
    float ss = v0 * v0 + v1 * v1;
    #pragma unroll
    for (int off = 32; off > 0; off >>= 1) ss += __shfl_xor(ss, off, 64);
    const float inv = 1.0f / fmaxf(sqrtf(ss), 1e-12f);
    *(float2*)(out + (size_t)node * OUT_DIM + c0) =
        make_float2(v0 * inv, v1 * inv);
}

// ---------------------------------------------------------------------------
extern "C" void kernel_launch(void* const* d_in, const int* in_sizes, int n_in,
                              void* d_out, int out_size, void* d_ws, size_t ws_size,
                              hipStream_t stream) {
    const float* x  = (const float*)d_in[0];
    const float* A  = (const float*)d_in[1];
    const float* W1 = (const float*)d_in[2];
    const float* b1 = (const float*)d_in[3];
    const float* W2 = (const float*)d_in[4];
    const float* b2 = (const float*)d_in[5];

    float* out = (float*)d_out;
    float* z2  = out;                                   // 16384 x 128
    float* z1  = out + (size_t)N_NODES * OUT_DIM;       // 16384 x 256

    char* p = (char*)d_ws;
    int*   adj = (int*)p;            p += (size_t)N_NODES * MAXDEG * sizeof(int);
    int*   cnt = (int*)p;            p += (size_t)N_NODES * sizeof(int);
    float* din = (float*)p;          p += (size_t)N_NODES * sizeof(float);
    unsigned short* h1 = (unsigned short*)p;
    p += (size_t)N_NODES * HID_DIM * sizeof(unsigned short);
    unsigned short* z1b = (unsigned short*)p;
    p += (size_t)N_NODES * HID_DIM * sizeof(unsigned short);
    unsigned short* h2 = (unsigned short*)p;
    p += (size_t)N_NODES * OUT_DIM * sizeof(unsigned short);
    unsigned short* W1T = (unsigned short*)p;           // 256 x 512 bf16

    // 1) W1T = bf16(W1^T)
    w1t_kernel<<<dim3(IN_DIM / 64, HID_DIM / 64), 256, 0, stream>>>(W1, W1T);

    // 2) h1 = bf16(x @ W1) via MFMA
    gemm1_mfma_kernel<<<N_NODES / 64, 256, 0, stream>>>(x, W1T, h1);

    // 3) adjacency scan (pure, full occupancy)
    scan_kernel<<<N_NODES / 4, 256, 0, stream>>>(A, adj, cnt, din);

    // 4) z1 = l2norm(elu(agg(h1*din)*din + b1)) -> f32 out + bf16 ws
    agg1_kernel<<<N_NODES / 4, 256, 0, stream>>>(
        h1, adj, cnt, din, b1, z1, z1b);

    // 5) h2 = bf16(z1b @ W2) via MFMA
    gemm2_mfma_kernel<<<N_NODES / 64, 256, 0, stream>>>(z1b, W2, h2);

    // 6) z2 = l2norm(agg(h2*din)*din + b2) -> f32
    agg2_kernel<<<N_NODES / 4, 256, 0, stream>>>(h2, adj, cnt, din, b2, z2);
}